// Round 5
// baseline (1865.214 us; speedup 1.0000x reference)
//
#include <hip/hip_runtime.h>
#include <hip/hip_bf16.h>
#include <math.h>

#define NT 1024
#define BSZ 128
#define TSTEPS 32
#define DIN 128
#define DHH 128
#define NSLOT 512
#define NMY 256
#define EPSF 1e-8f

// LDS: [0,65536) mem bf16[256][128] XOR-swizzled; then float scratch F[7160]
static constexpr int F_FLOATS = 7160;
static constexpr size_t LDS_BYTES = 65536 + F_FLOATS * sizeof(float);

// Workspace layout per batch element (float offsets, stride 512 floats):
//   S1: [0..31]   2 halves x 16: {sumER, sumEW, eR@{0,1,254,255}, eW@{0,1,254,255}}
//   S2: [32..33]  P1 partials     S3: [34..35] P2 partials
//   S4r:[64..319] 2 halves x 128 r partials
//   S4p:[320..327] 2 halves x 4 raw p2 @ local {0,1,254,255}
//   FLG:[352]     2 x u32 monotonic tokens
#define WSTRIDE 512
#define S1OFF 0
#define S2OFF 32
#define S3OFF 34
#define S4R   64
#define S4P   320
#define FLG   352

__device__ __forceinline__ float bf_lo(unsigned u) {
  union { unsigned u; float f; } c; c.u = u << 16; return c.f;
}
__device__ __forceinline__ float bf_hi(unsigned u) {
  union { unsigned u; float f; } c; c.u = u & 0xffff0000u; return c.f;
}
__device__ __forceinline__ unsigned short f2us(float f) {
  union { unsigned short s; __hip_bfloat16 h; } c; c.h = __float2bfloat16(f); return c.s;
}
__device__ __forceinline__ unsigned pkbf(float a, float b) {
  union { __hip_bfloat162 h2; unsigned u; } c;
  c.h2 = __float22bfloat162_rn(make_float2(a, b));
  return c.u;
}
__device__ __forceinline__ float sigmoid_(float x) { return 1.0f / (1.0f + __expf(-x)); }
__device__ __forceinline__ float softplus_(float x) {
  return fmaxf(x, 0.0f) + log1pf(__expf(-fabsf(x)));
}
__device__ __forceinline__ float tanh_(float x) {
  float e = __expf(-2.0f * fabsf(x));
  float t = (1.0f - e) / (1.0f + e);
  return copysignf(t, x);
}
__device__ __forceinline__ float waveSum(float v) {
#pragma unroll
  for (int m = 32; m >= 1; m >>= 1) v += __shfl_xor(v, m);
  return v;
}
__device__ __forceinline__ void bar_lds() {
  asm volatile("s_waitcnt lgkmcnt(0)" ::: "memory");
  __builtin_amdgcn_s_barrier();
}
// agent-scope (device) workspace accessors: bypass L1, visible cross-XCD
__device__ __forceinline__ void st_ws(float* p, float v) {
  __hip_atomic_store(p, v, __ATOMIC_RELAXED, __HIP_MEMORY_SCOPE_AGENT);
}
__device__ __forceinline__ float ld_ws(const float* p) {
  return __hip_atomic_load(p, __ATOMIC_RELAXED, __HIP_MEMORY_SCOPE_AGENT);
}

// R5: pair-split. 256 blocks; pair (b, b+128) co-computes batch b.
// Each block owns slots [half*256, half*256+256). Head compute (Seg1/2/3/F)
// is redundant+deterministic in both blocks (identical inputs -> identical
// bits). Slot segments (6,7,8,9,11) halved. 4 rendezvous/step via agent-scope
// atomics in ws: s1{E-sums + eR/eW 2-deep halo}, s2{P1}, s3{P2},
// s4{r-partial + raw-p2 halo}. Shift-conv halos handled by computing
// alpha on [s0-1..s0+256] locally from 2-deep eR/w_prev ghosts.
// Co-residency: 256 blocks = 256 CUs, 94KB LDS = 1 block/CU.
__global__ __launch_bounds__(NT, 4)
void ntm_kernel(const float* __restrict__ x,
                const float* __restrict__ Wxh,
                const float* __restrict__ Whh,
                const float* __restrict__ Wrh,
                const float* __restrict__ bh,
                const float* __restrict__ Wout,
                const float* __restrict__ bout,
                const float* __restrict__ Wr,
                const float* __restrict__ br,
                const float* __restrict__ Ww,
                const float* __restrict__ bw,
                float* __restrict__ ws,
                float* __restrict__ out)
{
  extern __shared__ char smem[];
  uint4* memv = (uint4*)smem;              // bf16 mem, LOCAL row nl = 16 uint4 (swizzled)
  float* F = (float*)(smem + 65536);

  const int b    = blockIdx.x & 127;       // batch element
  const int half = blockIdx.x >> 7;        // 0: slots 0..255, 1: slots 256..511
  const int s0   = half * NMY;
  const int tid = threadIdx.x;
  const int g = tid >> 4, l = tid & 15;    // Seg-9 mapping
  const int lane = tid & 63, wid = tid >> 6;

  float* U      = F + 0;      // 2560 multi-use: O/H partials; eR/eW; p2raw
  float* yP     = F + 2560;   // 2048 Y partials (live across step boundary)
  float* sWprev = F + 4608;   // 512 (full index space; ghosts filled via s4)
  float* sWr    = F + 5120;   // 512
  float* sP1    = F + 5632;   // 512 p1; aliased early by krP/kwP packed keys
  float* sOr    = F + 6144;   // 144 (134 used)
  float* sOw    = F + 6288;   // 392: [0..127] k_w, [136..263] e, [264..391] a
  float* sXt    = F + 6680;   // 128  } contiguous V[384] = [x | h | r]
  float* sH     = F + 6808;   // 128  }
  float* sR     = F + 6936;   // 128  } Seg-9 ds_add target; full r after s4
  float* sP     = F + 7064;   // 96: [0]kr2 [1]kw2 [2]SR [3]SW [4]P1 [5]P2; [80..91] scalars
  float* V      = sXt;
  uint4* krP    = (uint4*)(sP1 + 0);
  uint4* kwP    = (uint4*)(sP1 + 64);
  float* eR     = U + 0;
  float* eW     = U + 512;

  float* WS = ws + (size_t)b * WSTRIDE;
  unsigned* flg = (unsigned*)(WS + FLG);
  // ghost slot targets (abs index) receiving partner's local {0,1,254,255}
  const int tg0 = (s0 + 256) & 511;
  const int tg1 = (s0 + 257) & 511;
  const int tg2 = (s0 + 510) & 511;   // s0-2 mod 512
  const int tg3 = (s0 + 511) & 511;   // s0-1 mod 512

  // ---- init ----
  {
    const unsigned short mb = f2us(1e-6f);
    const unsigned w32 = ((unsigned)mb << 16) | mb;
    const uint4 fv = make_uint4(w32, w32, w32, w32);
    for (int i = tid; i < NMY * DHH / 8; i += NT) memv[i] = fv;
  }
  for (int i = tid; i < NSLOT; i += NT) sWprev[i] = 1.0f / NSLOT;
  if (tid < DHH) { sH[tid] = 0.0f; sR[tid] = 0.0f; }
  if (tid < DIN) sXt[tid] = x[(size_t)b * TSTEPS * DIN + tid];
  __syncthreads();

  for (int t = 0; t < TSTEPS; ++t) {
    // ==== Seg 1: H partials (redundant in both halves) ====
    {
      const int q = tid & 63, s = tid >> 6;
      const int j2 = q * 2, i0 = s * 24;
      float2 acc = make_float2(0.f, 0.f);
#pragma unroll 2
      for (int k = 0; k < 6; ++k) {
        const float4 vv = *(const float4*)(V + i0 + 4 * k);
        const float vk[4] = { vv.x, vv.y, vv.z, vv.w };
#pragma unroll
        for (int u = 0; u < 4; ++u) {
          const int i = i0 + 4 * k + u;
          const float* Wp = (i < 128) ? (Wxh + i * DHH)
                          : (i < 256) ? (Whh + (i - 128) * DHH)
                                      : (Wrh + (i - 256) * DHH);
          const float2 wv = *(const float2*)(Wp + j2);
          acc.x = fmaf(vk[u], wv.x, acc.x);
          acc.y = fmaf(vk[u], wv.y, acc.y);
        }
      }
      *(float2*)(U + s * 128 + j2) = acc;
      bar_lds();
    }
    // ==== Seg 2: h = tanh(sum + bh) ====
    if (tid < DHH) {
      float a2 = bh[tid];
#pragma unroll
      for (int q2 = 0; q2 < 16; ++q2) a2 += U[q2 * 128 + tid];
      sH[tid] = tanh_(a2);
    }
    bar_lds();

    // ==== Seg 3: O partials (redundant) ====
    {
      {
        const int s = tid;
        const int q = (s >= 786) ? 3 : (s >= 524) ? 2 : (s >= 262) ? 1 : 0;
        const int P = s - 262 * q;
        const int i0 = 32 * q;
        const float2* p;
        int strideF2;
        if (P < 67) { p = (const float2*)(Wr + i0 * 134 + 2 * P); strideF2 = 67; }
        else        { p = (const float2*)(Ww + i0 * 390 + 2 * (P - 67)); strideF2 = 195; }
        float2 acc = make_float2(0.f, 0.f);
#pragma unroll 2
        for (int k = 0; k < 8; ++k) {
          const float4 hv = *(const float4*)(sH + i0 + 4 * k);
          const float hk[4] = { hv.x, hv.y, hv.z, hv.w };
#pragma unroll
          for (int u = 0; u < 4; ++u) {
            const float2 wv = p[(4 * k + u) * strideF2];
            acc.x = fmaf(hk[u], wv.x, acc.x);
            acc.y = fmaf(hk[u], wv.y, acc.y);
          }
        }
        *(float2*)(U + s * 2) = acc;
      }
      if (lane < 3) {
        const int hs = wid * 3 + lane;
        const int e = hs >> 1, hh = hs & 1;
        const int cp = 171 + e;
        const int i0 = 96 + 16 * hh;
        const float2* p = (const float2*)(Ww + i0 * 390 + 2 * cp);
        float2 acc = make_float2(0.f, 0.f);
#pragma unroll 8
        for (int w = 0; w < 16; ++w) {
          const float v = sH[i0 + w];
          const float2 wv = *p;
          acc.x = fmaf(v, wv.x, acc.x);
          acc.y = fmaf(v, wv.y, acc.y);
          p += 195;
        }
        U[2096 + hs * 2]     = acc.x;
        U[2096 + hs * 2 + 1] = acc.y;
      }
      if (tid == 1023) {
        sP[0] = 0.f; sP[1] = 0.f; sP[2] = 0.f; sP[3] = 0.f; sP[4] = 0.f; sP[5] = 0.f;
      }
      bar_lds();
    }

    // ==== Seg F: combine+bias / knorm / e,a / key packing / scalars /
    //      sR zero / y-finalize(t-1, my 64 cols) ====
    {
      if (tid < 134) {
        float v = 0.f;
#pragma unroll
        for (int q = 0; q < 4; ++q) v += U[tid + 524 * q];
        v += br[tid];
        sOr[tid] = v;
        if (tid < 128) {
          float s2 = waveSum(v * v);
          if (lane == 0) atomicAdd(&sP[0], s2);
        }
      } else if (tid == 134) {
        float sc[6];
#pragma unroll
        for (int j = 0; j < 6; ++j) {
          float v = 0.f;
#pragma unroll
          for (int q = 0; q < 4; ++q) v += U[(128 + j) + 524 * q];
          sc[j] = v + br[128 + j];
        }
        sP[80] = softplus_(sc[0]);
        sP[81] = sigmoid_(sc[1]);
        float mx = fmaxf(sc[2], fmaxf(sc[3], sc[4]));
        float e0 = __expf(sc[2] - mx), e1 = __expf(sc[3] - mx), e2 = __expf(sc[4] - mx);
        float es = e0 + e1 + e2;
        sP[82] = e0 / es; sP[83] = e1 / es; sP[84] = e2 / es;
        sP[85] = 1.0f + softplus_(sc[5]);
      } else if (tid == 135) {
        float sc[6];
#pragma unroll
        for (int j = 0; j < 6; ++j) {
          float v = 0.f;
#pragma unroll
          for (int q = 0; q < 4; ++q) v += U[(262 + j) + 524 * q];
          sc[j] = v + bw[128 + j];
        }
        sP[86] = softplus_(sc[0]);
        sP[87] = sigmoid_(sc[1]);
        float mx = fmaxf(sc[2], fmaxf(sc[3], sc[4]));
        float e0 = __expf(sc[2] - mx), e1 = __expf(sc[3] - mx), e2 = __expf(sc[4] - mx);
        float es = e0 + e1 + e2;
        sP[88] = e0 / es; sP[89] = e1 / es; sP[90] = e2 / es;
        sP[91] = 1.0f + softplus_(sc[5]);
      } else if (tid >= 256 && tid < 512) {
        const int cc = tid + 12;
        float v = U[cc] + U[cc + 524] + U[cc + 1048];
        if (cc < 476) {
          v += U[cc + 1572];
        } else {
          const int cw = cc - 134;
          const int e = (cw >> 1) - 171;
          const int base = 2096 + 4 * e + (cw & 1);
          v += U[base] + U[base + 2];
        }
        v += bw[tid - 122];
        sOw[tid - 120] = (tid < 384) ? sigmoid_(v) : tanh_(v);
      } else if (tid >= 512 && tid < 640) {
        const int cw = tid - 512;
        float v = 0.f;
#pragma unroll
        for (int q = 0; q < 4; ++q) v += U[(134 + cw) + 524 * q];
        v += bw[cw];
        sOw[cw] = v;
        float s2 = waveSum(v * v);
        if (lane == 0) atomicAdd(&sP[1], s2);
      } else if (tid >= 640 && tid < 768) {
        sR[tid - 640] = 0.f;
      } else if (tid >= 768 && tid < 800) {
        const int t2 = tid - 768;
        const int c = t2 & 15;
        union { uint4 v; unsigned short h[8]; } pk;
#pragma unroll
        for (int j = 0; j < 8; ++j) {
          const int col = c * 8 + j;
          float v = 0.f;
#pragma unroll
          for (int q = 0; q < 4; ++q)
            v += U[((t2 < 16) ? col : (134 + col)) + 524 * q];
          v += (t2 < 16) ? br[col] : bw[col];
          pk.h[j] = f2us(v);
        }
        if (t2 < 16) krP[c] = pk.v; else kwP[c] = pk.v;
      } else if (tid >= 896 && tid < 960) { // y-finalize(t-1): my 64 cols
        if (t > 0) {
          const int c = half * 64 + (tid - 896);
          float y = bout[c];
#pragma unroll
          for (int q = 0; q < 16; ++q) y += yP[q * 128 + c];
          out[((size_t)b * TSTEPS + (t - 1)) * DIN + c] = y;
        }
      }
      bar_lds();
    }

    // ==== Seg 6: dots+norm+exp for MY 256 slots (4 threads/slot) ====
    {
      const float kn_r = sqrtf(sP[0]);
      const float kn_w = sqrtf(sP[1]);
      const float beta_r = sP[80], beta_w = sP[86];
      const int nl = tid >> 2, qf = tid & 3;
      const int n  = s0 + nl;
      const int sw = (nl >> 2) & 3;
      float dr = 0.f, dw = 0.f, ss = 0.f;
#pragma unroll
      for (int c = 0; c < 4; ++c) {
        const int cl = qf * 4 + c;
        const uint4 mv = memv[nl * 16 + (cl ^ sw)];
        const uint4 kr = krP[cl];
        const uint4 kw = kwP[cl];
        const unsigned mw_[4] = { mv.x, mv.y, mv.z, mv.w };
        const unsigned krw[4] = { kr.x, kr.y, kr.z, kr.w };
        const unsigned kww[4] = { kw.x, kw.y, kw.z, kw.w };
#pragma unroll
        for (int j = 0; j < 4; ++j) {
          const float m0 = bf_lo(mw_[j]), m1 = bf_hi(mw_[j]);
          dr = fmaf(m0, bf_lo(krw[j]), dr); dr = fmaf(m1, bf_hi(krw[j]), dr);
          dw = fmaf(m0, bf_lo(kww[j]), dw); dw = fmaf(m1, bf_hi(kww[j]), dw);
          ss = fmaf(m0, m0, ss);            ss = fmaf(m1, m1, ss);
        }
      }
      dr += __shfl_xor(dr, 1); dr += __shfl_xor(dr, 2);
      dw += __shfl_xor(dw, 1); dw += __shfl_xor(dw, 2);
      ss += __shfl_xor(ss, 1); ss += __shfl_xor(ss, 2);
      const float nr = sqrtf(ss);
      const float er = __expf(beta_r * dr / (nr * kn_r + EPSF));
      const float ew = __expf(beta_w * dw / (nr * kn_w + EPSF));
      if (qf == 0) { eR[n] = er; eW[n] = ew; }
      float s1_ = waveSum((qf == 0) ? er : 0.f);
      float s2_ = waveSum((qf == 0) ? ew : 0.f);
      if (lane == 0) { atomicAdd(&sP[2], s1_); atomicAdd(&sP[3], s2_); }
      bar_lds();
    }

    // ==== S1 rendezvous: E-sums + eR/eW 2-deep halo ====
    {
      const unsigned tok = (unsigned)(t * 4 + 1);
      float* myb = WS + S1OFF + half * 16;
      if (tid < 10) {
        float v;
        if (tid == 0)      v = sP[2];
        else if (tid == 1) v = sP[3];
        else if (tid < 6)  { const int k = tid - 2; v = eR[s0 + ((k < 2) ? k : k + 252)]; }
        else               { const int k = tid - 6; v = eW[s0 + ((k < 2) ? k : k + 252)]; }
        st_ws(myb + tid, v);
        __threadfence();
      }
      __builtin_amdgcn_s_barrier();
      if (tid == 0) {
        __hip_atomic_store(&flg[half], tok, __ATOMIC_RELEASE, __HIP_MEMORY_SCOPE_AGENT);
        while (__hip_atomic_load(&flg[1 - half], __ATOMIC_ACQUIRE, __HIP_MEMORY_SCOPE_AGENT) < tok)
          __builtin_amdgcn_s_sleep(1);
      }
      __builtin_amdgcn_s_barrier();
      float* ob = WS + S1OFF + (1 - half) * 16;
      if (tid < 10) {
        const float pv = ld_ws(ob + tid);
        if (tid == 0)      { const float my = sP[2]; sP[2] = half ? (pv + my) : (my + pv); }
        else if (tid == 1) { const float my = sP[3]; sP[3] = half ? (pv + my) : (my + pv); }
        else if (tid == 2) eR[tg0] = pv;
        else if (tid == 3) eR[tg1] = pv;
        else if (tid == 4) eR[tg2] = pv;
        else if (tid == 5) eR[tg3] = pv;
        else if (tid == 6) eW[tg0] = pv;
        else if (tid == 7) eW[tg1] = pv;
        else if (tid == 8) eW[tg2] = pv;
        else               eW[tg3] = pv;
      }
      bar_lds();
    }

    // ==== Seg 7: alpha on [s0-1 .. s0+256] (258 slots + halo) + Y-top ====
    {
      if (tid < 320) {                      // 5 whole waves; valid tid<258
        const bool av = (tid < 258);
        const int nn = (s0 - 1 + tid) & 511;
        const float invE = 1.0f / sP[2];
        const float gr = sP[81], omg = 1.0f - sP[81];
        const int im = (nn - 1) & 511, ip = (nn + 1) & 511;
        const float wgm = gr * (eR[im] * invE) + omg * sWprev[im];
        const float wg0 = gr * (eR[nn] * invE) + omg * sWprev[nn];
        const float wgp = gr * (eR[ip] * invE) + omg * sWprev[ip];
        const float wt = sP[82] * wgp + sP[83] * wg0 + sP[84] * wgm;
        float p1 = (wt > 0.0f) ? __expf(sP[85] * __logf(wt)) : 0.0f;
        float P = waveSum((tid >= 1 && tid <= 256) ? p1 : 0.f);
        if (av) sP1[nn] = p1;
        if (lane == 0) atomicAdd(&sP[4], P);
      } else if (tid >= 512 && tid < 768) { // Y-top: rows 0..127 x my 64 cols
        const int p = tid - 512;
        const int j4 = (p & 15) * 4 + half * 64, sl = p >> 4;
        float4 acc = make_float4(0.f, 0.f, 0.f, 0.f);
#pragma unroll
        for (int w = 0; w < 8; ++w) {
          const float v = sH[8 * sl + w];
          const float4 wv = *(const float4*)(Wout + (8 * sl + w) * DIN + j4);
          acc.x = fmaf(v, wv.x, acc.x); acc.y = fmaf(v, wv.y, acc.y);
          acc.z = fmaf(v, wv.z, acc.z); acc.w = fmaf(v, wv.w, acc.w);
        }
        *(float4*)(yP + sl * 128 + j4) = acc;
      }
      bar_lds();
    }

    // ==== S2 rendezvous: P1 ====
    {
      const unsigned tok = (unsigned)(t * 4 + 2);
      if (tid == 0) {
        const float my = sP[4];
        st_ws(WS + S2OFF + half, my);
        __threadfence();
        __hip_atomic_store(&flg[half], tok, __ATOMIC_RELEASE, __HIP_MEMORY_SCOPE_AGENT);
        while (__hip_atomic_load(&flg[1 - half], __ATOMIC_ACQUIRE, __HIP_MEMORY_SCOPE_AGENT) < tok)
          __builtin_amdgcn_s_sleep(1);
        const float pv = ld_ws(WS + S2OFF + (1 - half));
        sP[4] = half ? (pv + my) : (my + pv);
      }
      bar_lds();
    }

    // ==== Seg 8: beta on MY 256 slots + x prefetch ====
    {
      if (tid < NMY) {
        const int n = s0 + tid;
        const float pinv1 = 1.0f / (sP[4] + EPSF);
        const float invE = 1.0f / sP[3];
        const float gw = sP[87], omg = 1.0f - sP[87];
        const int im = (n - 1) & 511, ip = (n + 1) & 511;
        const float wgm = gw * (eW[im] * invE) + omg * (sP1[im] * pinv1);
        const float wg0 = gw * (eW[n] * invE) + omg * (sP1[n] * pinv1);
        const float wgp = gw * (eW[ip] * invE) + omg * (sP1[ip] * pinv1);
        sWr[n] = sP1[n] * pinv1;
        const float wt = sP[88] * wgp + sP[89] * wg0 + sP[90] * wgm;
        float p2 = (wt > 0.0f) ? __expf(sP[91] * __logf(wt)) : 0.0f;
        float P = waveSum(p2);
        U[n] = p2;                          // raw p2 (eR region, dead)
        if (lane == 0) atomicAdd(&sP[5], P);
      } else if (tid >= 512 && tid < 512 + DIN && t + 1 < TSTEPS) {
        const int i = tid - 512;
        sXt[i] = x[((size_t)b * TSTEPS + (t + 1)) * DIN + i];
      }
      bar_lds();
    }

    // ==== S3 rendezvous: P2 ====
    {
      const unsigned tok = (unsigned)(t * 4 + 3);
      if (tid == 0) {
        const float my = sP[5];
        st_ws(WS + S3OFF + half, my);
        __threadfence();
        __hip_atomic_store(&flg[half], tok, __ATOMIC_RELEASE, __HIP_MEMORY_SCOPE_AGENT);
        while (__hip_atomic_load(&flg[1 - half], __ATOMIC_ACQUIRE, __HIP_MEMORY_SCOPE_AGENT) < tok)
          __builtin_amdgcn_s_sleep(1);
        const float pv = ld_ws(WS + S3OFF + (1 - half));
        sP[5] = half ? (pv + my) : (my + pv);
      }
      bar_lds();
    }

    // ==== Seg 9: w_w inline; r-sweep + mem update over MY 256 slots ====
    {
      const float pinv2 = 1.0f / (sP[5] + EPSF);
      if (tid < NMY) sWprev[s0 + tid] = U[s0 + tid] * pinv2;

      const int cl = l ^ ((g >> 2) & 3);
      float4 e4a = *(const float4*)(sOw + 136 + cl * 8);
      float4 e4b = *(const float4*)(sOw + 140 + cl * 8);
      float4 a4a = *(const float4*)(sOw + 264 + cl * 8);
      float4 a4b = *(const float4*)(sOw + 268 + cl * 8);
      const float e8[8] = { e4a.x, e4a.y, e4a.z, e4a.w, e4b.x, e4b.y, e4b.z, e4b.w };
      const float a8[8] = { a4a.x, a4a.y, a4a.z, a4a.w, a4b.x, a4b.y, a4b.z, a4b.w };
      float r8[8] = { 0, 0, 0, 0, 0, 0, 0, 0 };
#pragma unroll 2
      for (int it = 0; it < 4; ++it) {
        const int nl = g + 64 * it;
        const int n  = s0 + nl;
        const float wrn = sWr[n];
        const float wwn = U[n] * pinv2;
        uint4 pk = memv[nl * 16 + l];
        const unsigned wds[4] = { pk.x, pk.y, pk.z, pk.w };
        float m[8];
#pragma unroll
        for (int j = 0; j < 4; ++j) { m[2 * j] = bf_lo(wds[j]); m[2 * j + 1] = bf_hi(wds[j]); }
#pragma unroll
        for (int j = 0; j < 8; ++j) {
          r8[j] = fmaf(wrn, m[j], r8[j]);
          const float d = fmaf(-e8[j], m[j], a8[j]);
          m[j] = fmaf(wwn, d, m[j]);
        }
        pk.x = pkbf(m[0], m[1]);
        pk.y = pkbf(m[2], m[3]);
        pk.z = pkbf(m[4], m[5]);
        pk.w = pkbf(m[6], m[7]);
        memv[nl * 16 + l] = pk;
      }
#pragma unroll
      for (int j = 0; j < 8; ++j) {
        r8[j] += __shfl_xor(r8[j], 16);
        r8[j] += __shfl_xor(r8[j], 32);
      }
      if (lane < 16) {
#pragma unroll
        for (int j = 0; j < 8; ++j) atomicAdd(&sR[cl * 8 + j], r8[j]);
      }
      bar_lds();
    }

    // ==== S4 rendezvous: r partials + raw-p2 halo ====
    {
      const unsigned tok = (unsigned)(t * 4 + 4);
      float myr = 0.f;
      if (tid < 128) {
        myr = sR[tid];
        st_ws(WS + S4R + half * 128 + tid, myr);
        __threadfence();
      } else if (tid < 132) {
        const int k = tid - 128;
        st_ws(WS + S4P + half * 4 + k, U[s0 + ((k < 2) ? k : k + 252)]);
        __threadfence();
      }
      __builtin_amdgcn_s_barrier();
      if (tid == 0) {
        __hip_atomic_store(&flg[half], tok, __ATOMIC_RELEASE, __HIP_MEMORY_SCOPE_AGENT);
        while (__hip_atomic_load(&flg[1 - half], __ATOMIC_ACQUIRE, __HIP_MEMORY_SCOPE_AGENT) < tok)
          __builtin_amdgcn_s_sleep(1);
      }
      __builtin_amdgcn_s_barrier();
      if (tid < 128) {
        const float pv = ld_ws(WS + S4R + (1 - half) * 128 + tid);
        sR[tid] = half ? (pv + myr) : (myr + pv);   // full r, identical order in pair
      } else if (tid < 132) {
        const int k = tid - 128;
        const float pv = ld_ws(WS + S4P + (1 - half) * 4 + k);
        const float pinv2 = 1.0f / (sP[5] + EPSF);
        const int tgt = (k == 0) ? tg0 : (k == 1) ? tg1 : (k == 2) ? tg2 : tg3;
        sWprev[tgt] = pv * pinv2;
      }
      bar_lds();
    }

    // ==== Seg 11: Y-bottom rows 128..255 x my 64 cols ====
    {
      if (tid < 256) {
        const int j4 = (tid & 15) * 4 + half * 64, sl = tid >> 4;
        float4 acc = *(const float4*)(yP + sl * 128 + j4);
#pragma unroll
        for (int w = 0; w < 8; ++w) {
          const float v = sR[8 * sl + w];
          const float4 wv = *(const float4*)(Wout + (128 + 8 * sl + w) * DIN + j4);
          acc.x = fmaf(v, wv.x, acc.x); acc.y = fmaf(v, wv.y, acc.y);
          acc.z = fmaf(v, wv.z, acc.z); acc.w = fmaf(v, wv.w, acc.w);
        }
        *(float4*)(yP + sl * 128 + j4) = acc;
      }
      bar_lds();
    }
  }

  // final y: my 64 cols
  if (tid < 64) {
    const int c = half * 64 + tid;
    float y = bout[c];
#pragma unroll
    for (int q = 0; q < 16; ++q) y += yP[q * 128 + c];
    out[((size_t)b * TSTEPS + (TSTEPS - 1)) * DIN + c] = y;
  }
}

extern "C" void kernel_launch(void* const* d_in, const int* in_sizes, int n_in,
                              void* d_out, int out_size, void* d_ws, size_t ws_size,
                              hipStream_t stream) {
  (void)in_sizes; (void)n_in; (void)out_size; (void)ws_size;
  hipFuncSetAttribute(reinterpret_cast<const void*>(ntm_kernel),
                      hipFuncAttributeMaxDynamicSharedMemorySize, (int)LDS_BYTES);
  // zero pair-sync flags (and payload area) each launch; stream-ordered, capture-safe
  hipMemsetAsync(d_ws, 0, (size_t)BSZ * WSTRIDE * sizeof(float), stream);
  ntm_kernel<<<dim3(2 * BSZ), dim3(NT), LDS_BYTES, stream>>>(
      (const float*)d_in[0], (const float*)d_in[1], (const float*)d_in[2],
      (const float*)d_in[3], (const float*)d_in[4], (const float*)d_in[5],
      (const float*)d_in[6], (const float*)d_in[7], (const float*)d_in[8],
      (const float*)d_in[9], (const float*)d_in[10],
      (float*)d_ws, (float*)d_out);
}

// Round 6
// 857.451 us; speedup vs baseline: 2.1753x; 2.1753x over previous
//
#include <hip/hip_runtime.h>
#include <hip/hip_bf16.h>
#include <math.h>

#define NT 1024
#define BSZ 128
#define TSTEPS 32
#define DIN 128
#define DHH 128
#define NSLOT 512
#define EPSF 1e-8f

// LDS: [0,131072) mem bf16[512][128] XOR-swizzled; then float scratch F[7160]
static constexpr int F_FLOATS = 7160;
static constexpr size_t LDS_BYTES = 131072 + F_FLOATS * sizeof(float);

__device__ __forceinline__ float bf_lo(unsigned u) {
  union { unsigned u; float f; } c; c.u = u << 16; return c.f;
}
__device__ __forceinline__ float bf_hi(unsigned u) {
  union { unsigned u; float f; } c; c.u = u & 0xffff0000u; return c.f;
}
__device__ __forceinline__ unsigned short f2us(float f) {
  union { unsigned short s; __hip_bfloat16 h; } c; c.h = __float2bfloat16(f); return c.s;
}
__device__ __forceinline__ unsigned pkbf(float a, float b) {
  union { __hip_bfloat162 h2; unsigned u; } c;
  c.h2 = __float22bfloat162_rn(make_float2(a, b));
  return c.u;
}
__device__ __forceinline__ float sigmoid_(float x) { return 1.0f / (1.0f + __expf(-x)); }
__device__ __forceinline__ float softplus_(float x) {
  return fmaxf(x, 0.0f) + log1pf(__expf(-fabsf(x)));
}
__device__ __forceinline__ float tanh_(float x) {
  float e = __expf(-2.0f * fabsf(x));
  float t = (1.0f - e) / (1.0f + e);
  return copysignf(t, x);
}
__device__ __forceinline__ float waveSum(float v) {
#pragma unroll
  for (int m = 32; m >= 1; m >>= 1) v += __shfl_xor(v, m);
  return v;
}

// LDS-only barrier: waits LDS ops only, does NOT drain vmcnt, so the tail of
// each segment's in-flight global (weight) loads survives the barrier. All
// inter-thread traffic in this kernel is LDS (out is write-only), so
// lgkmcnt(0)+s_barrier gives full __syncthreads semantics here.
__device__ __forceinline__ void bar_lds() {
  asm volatile("s_waitcnt lgkmcnt(0)" ::: "memory");
  __builtin_amdgcn_s_barrier();
}

// One block (1024 threads) per batch element; all 32 steps in-block.
// mem in LDS, rows XOR-swizzled: stored uint4 slot u = c ^ ((n>>2)&3).
// HISTORY: R1-R3 spilled (64-VGPR hard budget; any batched/cross-barrier
// register panel -> scratch, 2.3GB traffic, 2ms). R5 pair-split across 2 CUs:
// occupancy 24->48% but 4 rendezvous/step cost ~10us/step -> 1865us. REJECTED.
// Conclusion: latency-bound serial 9-phase pipeline; optimize phase poles only.
// R6 = R4 (best: 813us dispatches) + two register-neutral serial-tail fixes:
//   A. SegF head scalars: 2 threads x 6 serial transcendental chains
//      -> 12 threads x 1 chain, softmax-3 via intra-wave __shfl.
//   B. Seg2: 16-deep dependent add chain on 128 threads
//      -> 8-deep on 256 threads (2/col) + shfl_xor combine.
__global__ __launch_bounds__(NT, 4)
void ntm_kernel(const float* __restrict__ x,
                const float* __restrict__ Wxh,
                const float* __restrict__ Whh,
                const float* __restrict__ Wrh,
                const float* __restrict__ bh,
                const float* __restrict__ Wout,
                const float* __restrict__ bout,
                const float* __restrict__ Wr,
                const float* __restrict__ br,
                const float* __restrict__ Ww,
                const float* __restrict__ bw,
                float* __restrict__ out)
{
  extern __shared__ char smem[];
  uint4* memv = (uint4*)smem;              // bf16 mem, row n = 16 uint4 (swizzled)
  float* F = (float*)(smem + 131072);

  const int b = blockIdx.x;
  const int tid = threadIdx.x;
  const int g = tid >> 4, l = tid & 15;    // Phase-B mapping
  const int lane = tid & 63, wid = tid >> 6;

  float* U      = F + 0;      // 2560 multi-use: O/H partials (incl. [2096..2191]
                              //      half-slot partials); eR/eW; p2raw
  float* yP     = F + 2560;   // 2048 Y partials (live across step boundary)
  float* sWprev = F + 4608;   // 512
  float* sWr    = F + 5120;   // 512
  float* sP1    = F + 5632;   // 512 p1; aliased early by krP/kwP packed keys
  float* sOr    = F + 6144;   // 144 (134 used)
  float* sOw    = F + 6288;   // 392: [0..127] k_w, [136..263] e (16B-aligned), [264..391] a
  float* sXt    = F + 6680;   // 128  } contiguous V[384] = [x | h | r]
  float* sH     = F + 6808;   // 128  }  (order matters for Seg1 float4 reads)
  float* sR     = F + 6936;   // 128  }  (ds_add target in Seg 9)
  float* sP     = F + 7064;   // 96: [0]kr2 [1]kw2 [2]SR [3]SW [4]P1 [5]P2; [80..91] scalars
  float* V      = sXt;        // V[i]: i<128 x, i<256 h, else r
  uint4* krP    = (uint4*)(sP1 + 0);
  uint4* kwP    = (uint4*)(sP1 + 64);
  float* eR     = U + 0;
  float* eW     = U + 512;

  // ---- init ----
  {
    const unsigned short mb = f2us(1e-6f);
    const unsigned w32 = ((unsigned)mb << 16) | mb;
    const uint4 fv = make_uint4(w32, w32, w32, w32);
    for (int i = tid; i < NSLOT * DHH / 8; i += NT) memv[i] = fv;
  }
  for (int i = tid; i < NSLOT; i += NT) sWprev[i] = 1.0f / NSLOT;
  if (tid < DHH) { sH[tid] = 0.0f; sR[tid] = 0.0f; }
  if (tid < DIN) sXt[tid] = x[(size_t)b * TSTEPS * DIN + tid];
  __syncthreads();

  for (int t = 0; t < TSTEPS; ++t) {
    // ==== Seg 1: H partials (float2 weights interleaved; float4 V reads) ====
    {
      const int q = tid & 63, s = tid >> 6;   // s == wid: wave-uniform rows
      const int j2 = q * 2, i0 = s * 24;
      float2 acc = make_float2(0.f, 0.f);
#pragma unroll 2
      for (int k = 0; k < 6; ++k) {
        const float4 vv = *(const float4*)(V + i0 + 4 * k);
        const float vk[4] = { vv.x, vv.y, vv.z, vv.w };
#pragma unroll
        for (int u = 0; u < 4; ++u) {
          const int i = i0 + 4 * k + u;
          const float* Wp = (i < 128) ? (Wxh + i * DHH)
                          : (i < 256) ? (Whh + (i - 128) * DHH)
                                      : (Wrh + (i - 256) * DHH);
          const float2 wv = *(const float2*)(Wp + j2);
          acc.x = fmaf(vk[u], wv.x, acc.x);
          acc.y = fmaf(vk[u], wv.y, acc.y);
        }
      }
      *(float2*)(U + s * 128 + j2) = acc;
      bar_lds();
    }
    // ==== Seg 2: h = tanh(sum + bh) — 2 threads/col, shfl-combined ====
    if (tid < 2 * DHH) {
      const int col = tid >> 1, ph = tid & 1;
      float p = 0.f;
#pragma unroll
      for (int q2 = 0; q2 < 8; ++q2) p += U[(8 * ph + q2) * 128 + col];
      p += __shfl_xor(p, 1);
      if (ph == 0) sH[col] = tanh_(bh[col] + p);
    }
    bar_lds();

    // ==== Seg 3: O partials — pass1 slot=tid (float4 sH reads); pass2 48
    //      half-slots, 3/wave (baseline form) ====
    {
      {
        const int s = tid;                  // 0..1023 (all valid, < 1048)
        const int q = (s >= 786) ? 3 : (s >= 524) ? 2 : (s >= 262) ? 1 : 0;
        const int P = s - 262 * q;
        const int i0 = 32 * q;
        const float2* p;
        int strideF2;
        if (P < 67) { p = (const float2*)(Wr + i0 * 134 + 2 * P); strideF2 = 67; }
        else        { p = (const float2*)(Ww + i0 * 390 + 2 * (P - 67)); strideF2 = 195; }
        float2 acc = make_float2(0.f, 0.f);
#pragma unroll 2
        for (int k = 0; k < 8; ++k) {
          const float4 hv = *(const float4*)(sH + i0 + 4 * k);
          const float hk[4] = { hv.x, hv.y, hv.z, hv.w };
#pragma unroll
          for (int u = 0; u < 4; ++u) {
            const float2 wv = p[(4 * k + u) * strideF2];
            acc.x = fmaf(hk[u], wv.x, acc.x);
            acc.y = fmaf(hk[u], wv.y, acc.y);
          }
        }
        *(float2*)(U + s * 2) = acc;
      }
      if (lane < 3) {                       // 48 half-slots: former slots 1024..1047
        const int hs = wid * 3 + lane;      // 0..47
        const int e = hs >> 1, hh = hs & 1;
        const int cp = 171 + e;             // Ww col-pair (P = 238+e >= 67)
        const int i0 = 96 + 16 * hh;
        const float2* p = (const float2*)(Ww + i0 * 390 + 2 * cp);
        float2 acc = make_float2(0.f, 0.f);
#pragma unroll 8
        for (int w = 0; w < 16; ++w) {
          const float v = sH[i0 + w];
          const float2 wv = *p;
          acc.x = fmaf(v, wv.x, acc.x);
          acc.y = fmaf(v, wv.y, acc.y);
          p += 195;
        }
        U[2096 + hs * 2]     = acc.x;
        U[2096 + hs * 2 + 1] = acc.y;
      }
      if (tid == 1023) {
        sP[0] = 0.f; sP[1] = 0.f; sP[2] = 0.f; sP[3] = 0.f; sP[4] = 0.f; sP[5] = 0.f;
      }
      bar_lds();
    }

    // ==== Seg F: fused combine+bias / knorm / e,a transforms / key packing /
    //      head scalars (12-thread parallel) / sR zeroing / y-finalize(t-1) ====
    {
      if (tid < 134) {                      // o_r col tid
        float v = 0.f;
#pragma unroll
        for (int q = 0; q < 4; ++q) v += U[tid + 524 * q];
        v += br[tid];
        sOr[tid] = v;
        if (tid < 128) {                    // waves 0,1 whole: |k_r|^2
          float s2 = waveSum(v * v);
          if (lane == 0) atomicAdd(&sP[0], s2);
        }
      } else if (tid < 146) {               // 12-thread parallel head scalars
        const int wh = (tid >= 140) ? 1 : 0; // 0=read head, 1=write head
        const int j  = tid - 134 - 6 * wh;   // 0..5
        const int colU = (wh ? 262 : 128) + j;
        float sc = 0.f;
#pragma unroll
        for (int q = 0; q < 4; ++q) sc += U[colU + 524 * q];
        sc += wh ? bw[128 + j] : br[128 + j];
        const int bl = 6 + 6 * wh;           // lane of this head's j==0 (wave 2)
        const int o  = wh ? 86 : 80;
        if (j == 0)      sP[o + 0] = softplus_(sc);
        else if (j == 1) sP[o + 1] = sigmoid_(sc);
        else if (j == 5) sP[o + 5] = 1.0f + softplus_(sc);
        else {                               // j in {2,3,4}: softmax-3 via shfl
          const float s0v = __shfl(sc, bl + 2);
          const float s1v = __shfl(sc, bl + 3);
          const float s2v = __shfl(sc, bl + 4);
          const float mx = fmaxf(s0v, fmaxf(s1v, s2v));
          const float e0 = __expf(s0v - mx), e1 = __expf(s1v - mx), e2 = __expf(s2v - mx);
          const float es = e0 + e1 + e2;
          const float r3 = (j == 2) ? e0 : (j == 3) ? e1 : e2;
          sP[o + j] = r3 / es;
        }
      } else if (tid >= 256 && tid < 512) { // e (256..383) / a (384..511)
        const int cc = tid + 12;            // combined col = 134 + cw, cw = tid-122
        float v = U[cc] + U[cc + 524] + U[cc + 1048];
        if (cc < 476) {
          v += U[cc + 1572];
        } else {                            // q=3 partial split into 2 halves
          const int cw = cc - 134;          // 342..389
          const int e = (cw >> 1) - 171;    // 0..23
          const int base = 2096 + 4 * e + (cw & 1);
          v += U[base] + U[base + 2];
        }
        v += bw[tid - 122];
        sOw[tid - 120] = (tid < 384) ? sigmoid_(v) : tanh_(v);
      } else if (tid >= 512 && tid < 640) { // k_w col cw (waves 8,9 whole): |k_w|^2
        const int cw = tid - 512;
        float v = 0.f;
#pragma unroll
        for (int q = 0; q < 4; ++q) v += U[(134 + cw) + 524 * q];
        v += bw[cw];
        sOw[cw] = v;
        float s2 = waveSum(v * v);
        if (lane == 0) atomicAdd(&sP[1], s2);
      } else if (tid >= 640 && tid < 768) {
        sR[tid - 640] = 0.f;                // Seg-9 ds_add target
      } else if (tid >= 768 && tid < 800) { // bf16 key packing from U (redundant combine)
        const int t2 = tid - 768;
        const int c = t2 & 15;
        union { uint4 v; unsigned short h[8]; } pk;
#pragma unroll
        for (int j = 0; j < 8; ++j) {
          const int col = c * 8 + j;        // 0..127
          float v = 0.f;
#pragma unroll
          for (int q = 0; q < 4; ++q)
            v += U[((t2 < 16) ? col : (134 + col)) + 524 * q];
          v += (t2 < 16) ? br[col] : bw[col];
          pk.h[j] = f2us(v);
        }
        if (t2 < 16) krP[c] = pk.v; else kwP[c] = pk.v;
      } else if (tid >= 896) {              // y-finalize(t-1) on idle waves 14,15
        if (t > 0) {
          const int c = tid - 896;
          float y = bout[c];
#pragma unroll
          for (int q = 0; q < 16; ++q) y += yP[q * 128 + c];
          out[((size_t)b * TSTEPS + (t - 1)) * DIN + c] = y;
        }
      }
      bar_lds();
    }

    // ==== Seg 6 (A): dots + norm + exp fused; bf16 keys; SR/SW via atomic ====
    {
      const float kn_r = sqrtf(sP[0]);
      const float kn_w = sqrtf(sP[1]);
      const float beta_r = sP[80], beta_w = sP[86];
      const int n = tid >> 1, hf = tid & 1;
      const int sw = (n >> 2) & 3;
      float dr = 0.f, dw = 0.f, ss = 0.f;
#pragma unroll
      for (int c = 0; c < 8; ++c) {
        const int cl = hf * 8 + c;
        const uint4 mv = memv[n * 16 + (cl ^ sw)];
        const uint4 kr = krP[cl];
        const uint4 kw = kwP[cl];
        const unsigned mw_[4] = { mv.x, mv.y, mv.z, mv.w };
        const unsigned krw[4] = { kr.x, kr.y, kr.z, kr.w };
        const unsigned kww[4] = { kw.x, kw.y, kw.z, kw.w };
#pragma unroll
        for (int j = 0; j < 4; ++j) {
          const float m0 = bf_lo(mw_[j]), m1 = bf_hi(mw_[j]);
          dr = fmaf(m0, bf_lo(krw[j]), dr); dr = fmaf(m1, bf_hi(krw[j]), dr);
          dw = fmaf(m0, bf_lo(kww[j]), dw); dw = fmaf(m1, bf_hi(kww[j]), dw);
          ss = fmaf(m0, m0, ss);            ss = fmaf(m1, m1, ss);
        }
      }
      dr += __shfl_xor(dr, 1);
      dw += __shfl_xor(dw, 1);
      ss += __shfl_xor(ss, 1);
      const float nr = sqrtf(ss);
      const float er = __expf(beta_r * dr / (nr * kn_r + EPSF));
      const float ew = __expf(beta_w * dw / (nr * kn_w + EPSF));
      if (hf == 0) { eR[n] = er; eW[n] = ew; }
      float s1 = waveSum(er) * 0.5f;
      float s2 = waveSum(ew) * 0.5f;
      if (lane == 0) { atomicAdd(&sP[2], s1); atomicAdd(&sP[3], s2); }
      bar_lds();
    }

    // ==== Seg 7: alpha (tid<512) + Y-top GEMV rows 0..127 (upper waves) ====
    {
      if (tid < NSLOT) {
        const float invE = 1.0f / sP[2];
        const float gr = sP[81], omg = 1.0f - sP[81];
        const int im = (tid - 1) & 511, ip = (tid + 1) & 511;
        const float wgm = gr * (eR[im] * invE) + omg * sWprev[im];
        const float wg0 = gr * (eR[tid] * invE) + omg * sWprev[tid];
        const float wgp = gr * (eR[ip] * invE) + omg * sWprev[ip];
        const float wt = sP[82] * wgp + sP[83] * wg0 + sP[84] * wgm;
        float p1 = (wt > 0.0f) ? __expf(sP[85] * __logf(wt)) : 0.0f;
        float P = waveSum(p1);
        sP1[tid] = p1;
        if (lane == 0) atomicAdd(&sP[4], P);
      } else {
        const int p = tid - 512;
        const int j4 = (p & 31) * 4, sl = p >> 5;   // 16 segs x 8 rows (0..127)
        float4 acc = make_float4(0.f, 0.f, 0.f, 0.f);
#pragma unroll
        for (int w = 0; w < 8; ++w) {
          const float v = sH[8 * sl + w];
          const float4 wv = *(const float4*)(Wout + (8 * sl + w) * DIN + j4);
          acc.x = fmaf(v, wv.x, acc.x); acc.y = fmaf(v, wv.y, acc.y);
          acc.z = fmaf(v, wv.z, acc.z); acc.w = fmaf(v, wv.w, acc.w);
        }
        *(float4*)(yP + sl * 128 + j4) = acc;
      }
      bar_lds();
    }
    // ==== Seg 8: beta (tid<512) + x prefetch (idle upper waves) ====
    {
      if (tid < NSLOT) {
        const float pinv1 = 1.0f / (sP[4] + EPSF);
        const float invE = 1.0f / sP[3];
        const float gw = sP[87], omg = 1.0f - sP[87];
        const int im = (tid - 1) & 511, ip = (tid + 1) & 511;
        const float wgm = gw * (eW[im] * invE) + omg * (sP1[im] * pinv1);
        const float wg0 = gw * (eW[tid] * invE) + omg * (sP1[tid] * pinv1);
        const float wgp = gw * (eW[ip] * invE) + omg * (sP1[ip] * pinv1);
        sWr[tid] = sP1[tid] * pinv1;
        const float wt = sP[88] * wgp + sP[89] * wg0 + sP[90] * wgm;
        float p2 = (wt > 0.0f) ? __expf(sP[91] * __logf(wt)) : 0.0f;
        float P = waveSum(p2);
        U[tid] = p2;                       // raw p2 (eR region, dead)
        if (lane == 0) atomicAdd(&sP[5], P);
      } else if (tid < 512 + DIN && t + 1 < TSTEPS) {
        const int i = tid - 512;
        sXt[i] = x[((size_t)b * TSTEPS + (t + 1)) * DIN + i];
      }
      bar_lds();
    }

    // ==== Seg 9 (B): w_w inline; r-sweep + mem update; r via ds_add into sR ====
    {
      const float pinv2 = 1.0f / (sP[5] + EPSF);
      if (tid < NSLOT) sWprev[tid] = U[tid] * pinv2;   // next step's w_prev

      const int cl = l ^ ((g >> 2) & 3);
      float4 e4a = *(const float4*)(sOw + 136 + cl * 8);
      float4 e4b = *(const float4*)(sOw + 140 + cl * 8);
      float4 a4a = *(const float4*)(sOw + 264 + cl * 8);
      float4 a4b = *(const float4*)(sOw + 268 + cl * 8);
      const float e8[8] = { e4a.x, e4a.y, e4a.z, e4a.w, e4b.x, e4b.y, e4b.z, e4b.w };
      const float a8[8] = { a4a.x, a4a.y, a4a.z, a4a.w, a4b.x, a4b.y, a4b.z, a4b.w };
      float r8[8] = { 0, 0, 0, 0, 0, 0, 0, 0 };
#pragma unroll 2
      for (int it = 0; it < 8; ++it) {
        const int n = g + 64 * it;
        const float wrn = sWr[n];
        const float wwn = U[n] * pinv2;
        uint4 pk = memv[n * 16 + l];
        const unsigned wds[4] = { pk.x, pk.y, pk.z, pk.w };
        float m[8];
#pragma unroll
        for (int j = 0; j < 4; ++j) { m[2 * j] = bf_lo(wds[j]); m[2 * j + 1] = bf_hi(wds[j]); }
#pragma unroll
        for (int j = 0; j < 8; ++j) {
          r8[j] = fmaf(wrn, m[j], r8[j]);
          const float d = fmaf(-e8[j], m[j], a8[j]);
          m[j] = fmaf(wwn, d, m[j]);
        }
        pk.x = pkbf(m[0], m[1]);
        pk.y = pkbf(m[2], m[3]);
        pk.z = pkbf(m[4], m[5]);
        pk.w = pkbf(m[6], m[7]);
        memv[n * 16 + l] = pk;
      }
#pragma unroll
      for (int j = 0; j < 8; ++j) {          // partners g^1,g^2 share chunk
        r8[j] += __shfl_xor(r8[j], 16);
        r8[j] += __shfl_xor(r8[j], 32);
      }
      if (lane < 16) {                       // 16 waves x 8 ds_add into sR
#pragma unroll
        for (int j = 0; j < 8; ++j) atomicAdd(&sR[cl * 8 + j], r8[j]);
      }
      bar_lds();
    }

    // ==== Seg 11: Y-bottom GEMV rows 128..255 (tid<512), accumulate into yP ====
    {
      if (tid < 512) {
        const int j4 = (tid & 31) * 4, sl = tid >> 5;   // 16 segs x 8 rows
        float4 acc = *(const float4*)(yP + sl * 128 + j4);
#pragma unroll
        for (int w = 0; w < 8; ++w) {
          const float v = sR[8 * sl + w];
          const float4 wv = *(const float4*)(Wout + (128 + 8 * sl + w) * DIN + j4);
          acc.x = fmaf(v, wv.x, acc.x); acc.y = fmaf(v, wv.y, acc.y);
          acc.z = fmaf(v, wv.z, acc.z); acc.w = fmaf(v, wv.w, acc.w);
        }
        *(float4*)(yP + sl * 128 + j4) = acc;
      }
      bar_lds();
    }
  }

  // final y
  if (tid < DIN) {
    float y = bout[tid];
#pragma unroll
    for (int q = 0; q < 16; ++q) y += yP[q * 128 + tid];
    out[((size_t)b * TSTEPS + (TSTEPS - 1)) * DIN + tid] = y;
  }
}

extern "C" void kernel_launch(void* const* d_in, const int* in_sizes, int n_in,
                              void* d_out, int out_size, void* d_ws, size_t ws_size,
                              hipStream_t stream) {
  (void)in_sizes; (void)n_in; (void)out_size; (void)d_ws; (void)ws_size;
  hipFuncSetAttribute(reinterpret_cast<const void*>(ntm_kernel),
                      hipFuncAttributeMaxDynamicSharedMemorySize, (int)LDS_BYTES);
  ntm_kernel<<<dim3(BSZ), dim3(NT), LDS_BYTES, stream>>>(
      (const float*)d_in[0], (const float*)d_in[1], (const float*)d_in[2],
      (const float*)d_in[3], (const float*)d_in[4], (const float*)d_in[5],
      (const float*)d_in[6], (const float*)d_in[7], (const float*)d_in[8],
      (const float*)d_in[9], (const float*)d_in[10],
      (float*)d_out);
}

// Round 7
// 841.816 us; speedup vs baseline: 2.2157x; 1.0186x over previous
//
#include <hip/hip_runtime.h>
#include <hip/hip_bf16.h>
#include <math.h>

#define NT 1024
#define BSZ 128
#define TSTEPS 32
#define DIN 128
#define DHH 128
#define NSLOT 512
#define EPSF 1e-8f

// LDS: [0,131072) mem bf16[512][128] XOR-swizzled; then float scratch F[7160]
static constexpr int F_FLOATS = 7160;
static constexpr size_t LDS_BYTES = 131072 + F_FLOATS * sizeof(float);

__device__ __forceinline__ float bf_lo(unsigned u) {
  union { unsigned u; float f; } c; c.u = u << 16; return c.f;
}
__device__ __forceinline__ float bf_hi(unsigned u) {
  union { unsigned u; float f; } c; c.u = u & 0xffff0000u; return c.f;
}
__device__ __forceinline__ unsigned short f2us(float f) {
  union { unsigned short s; __hip_bfloat16 h; } c; c.h = __float2bfloat16(f); return c.s;
}
__device__ __forceinline__ unsigned pkbf(float a, float b) {
  union { __hip_bfloat162 h2; unsigned u; } c;
  c.h2 = __float22bfloat162_rn(make_float2(a, b));
  return c.u;
}
__device__ __forceinline__ float sigmoid_(float x) { return 1.0f / (1.0f + __expf(-x)); }
__device__ __forceinline__ float softplus_(float x) {
  return fmaxf(x, 0.0f) + log1pf(__expf(-fabsf(x)));
}
__device__ __forceinline__ float tanh_(float x) {
  float e = __expf(-2.0f * fabsf(x));
  float t = (1.0f - e) / (1.0f + e);
  return copysignf(t, x);
}
__device__ __forceinline__ float waveSum(float v) {
#pragma unroll
  for (int m = 32; m >= 1; m >>= 1) v += __shfl_xor(v, m);
  return v;
}

// LDS-only barrier: waits LDS ops only, does NOT drain vmcnt, so the tail of
// each segment's in-flight global (weight) loads survives the barrier. All
// inter-thread traffic in this kernel is LDS (out is write-only), so
// lgkmcnt(0)+s_barrier gives full __syncthreads semantics here.
__device__ __forceinline__ void bar_lds() {
  asm volatile("s_waitcnt lgkmcnt(0)" ::: "memory");
  __builtin_amdgcn_s_barrier();
}

// One block (1024 threads) per batch element; all 32 steps in-block.
// mem in LDS, rows XOR-swizzled: stored uint4 slot u = c ^ ((n>>2)&3).
// HISTORY: R1-R3 spilled (64-VGPR hard budget -> scratch, 2.3GB, 2ms).
// R5 2-CU pair-split: occupancy 24->48% but 4 rendezvous/step ~10us -> 1865us.
// R6 serial-tail parallelization: neutral-to-negative (820 vs R4 813).
// R7 = R4 (best measured: 813us) + two issue-count cuts:
//   A. Seg9 scalar-pair merge: sWW[n]={w_r,p2raw} float2 written by Seg8 into
//      dead U[1024..2048) (O-partials region, dead SegF->next Seg3). Halves
//      Seg9's broadcast b32 DS reads (2->1 per iter).
//   B. Barrier fusion 9->8: Seg11 (Y-bottom, tid<512) moved into next
//      iteration's Seg1 (reads sR/yP which Seg1 doesn't write); epilogue
//      handles the final step's Seg11.
__global__ __launch_bounds__(NT, 4)
void ntm_kernel(const float* __restrict__ x,
                const float* __restrict__ Wxh,
                const float* __restrict__ Whh,
                const float* __restrict__ Wrh,
                const float* __restrict__ bh,
                const float* __restrict__ Wout,
                const float* __restrict__ bout,
                const float* __restrict__ Wr,
                const float* __restrict__ br,
                const float* __restrict__ Ww,
                const float* __restrict__ bw,
                float* __restrict__ out)
{
  extern __shared__ char smem[];
  uint4* memv = (uint4*)smem;              // bf16 mem, row n = 16 uint4 (swizzled)
  float* F = (float*)(smem + 131072);

  const int b = blockIdx.x;
  const int tid = threadIdx.x;
  const int g = tid >> 4, l = tid & 15;    // Phase-B mapping
  const int lane = tid & 63, wid = tid >> 6;

  float* U      = F + 0;      // 2560 multi-use: O/H partials (incl. [2096..2191]
                              //      half-slot partials); eR/eW; sWW overlay
  float* yP     = F + 2560;   // 2048 Y partials (live across step boundary)
  float* sWprev = F + 4608;   // 512
  float* sP1    = F + 5632;   // 512 p1; aliased early by krP/kwP packed keys
  float* sOr    = F + 6144;   // 144 (134 used)
  float* sOw    = F + 6288;   // 392: [0..127] k_w, [136..263] e (16B-aligned), [264..391] a
  float* sXt    = F + 6680;   // 128  } contiguous V[384] = [x | h | r]
  float* sH     = F + 6808;   // 128  }  (order matters for Seg1 float4 reads)
  float* sR     = F + 6936;   // 128  }  (ds_add target in Seg 9)
  float* sP     = F + 7064;   // 96: [0]kr2 [1]kw2 [2]SR [3]SW [4]P1 [5]P2; [80..91] scalars
  float* V      = sXt;        // V[i]: i<128 x, i<256 h, else r
  uint4* krP    = (uint4*)(sP1 + 0);
  uint4* kwP    = (uint4*)(sP1 + 64);
  float* eR     = U + 0;
  float* eW     = U + 512;
  float2* sWW2  = (float2*)(U + 1024);  // [512] {w_r, p2raw}; dead O-partials region

  // ---- init ----
  {
    const unsigned short mb = f2us(1e-6f);
    const unsigned w32 = ((unsigned)mb << 16) | mb;
    const uint4 fv = make_uint4(w32, w32, w32, w32);
    for (int i = tid; i < NSLOT * DHH / 8; i += NT) memv[i] = fv;
  }
  for (int i = tid; i < NSLOT; i += NT) sWprev[i] = 1.0f / NSLOT;
  if (tid < DHH) { sH[tid] = 0.0f; sR[tid] = 0.0f; }
  if (tid < DIN) sXt[tid] = x[(size_t)b * TSTEPS * DIN + tid];
  __syncthreads();

  for (int t = 0; t < TSTEPS; ++t) {
    // ==== Seg 1: H partials (float2 weights interleaved; float4 V reads)
    //      + embedded Seg11(t-1): Y-bottom GEMV on tid<512 (reads sR/yP,
    //      which Seg1 does not write) ====
    {
      const int q = tid & 63, s = tid >> 6;   // s == wid: wave-uniform rows
      const int j2 = q * 2, i0 = s * 24;
      float2 acc = make_float2(0.f, 0.f);
#pragma unroll 2
      for (int k = 0; k < 6; ++k) {
        const float4 vv = *(const float4*)(V + i0 + 4 * k);
        const float vk[4] = { vv.x, vv.y, vv.z, vv.w };
#pragma unroll
        for (int u = 0; u < 4; ++u) {
          const int i = i0 + 4 * k + u;
          const float* Wp = (i < 128) ? (Wxh + i * DHH)
                          : (i < 256) ? (Whh + (i - 128) * DHH)
                                      : (Wrh + (i - 256) * DHH);
          const float2 wv = *(const float2*)(Wp + j2);
          acc.x = fmaf(vk[u], wv.x, acc.x);
          acc.y = fmaf(vk[u], wv.y, acc.y);
        }
      }
      *(float2*)(U + s * 128 + j2) = acc;
      if (t > 0 && tid < 512) {             // Seg11(t-1)
        const int j4 = (tid & 31) * 4, sl = tid >> 5;
        float4 acc4 = *(const float4*)(yP + sl * 128 + j4);
#pragma unroll
        for (int w = 0; w < 8; ++w) {
          const float v = sR[8 * sl + w];
          const float4 wv = *(const float4*)(Wout + (128 + 8 * sl + w) * DIN + j4);
          acc4.x = fmaf(v, wv.x, acc4.x); acc4.y = fmaf(v, wv.y, acc4.y);
          acc4.z = fmaf(v, wv.z, acc4.z); acc4.w = fmaf(v, wv.w, acc4.w);
        }
        *(float4*)(yP + sl * 128 + j4) = acc4;
      }
      bar_lds();
    }
    // ==== Seg 2: h = tanh(sum + bh) ====
    if (tid < DHH) {
      float a2 = bh[tid];
#pragma unroll
      for (int q2 = 0; q2 < 16; ++q2) a2 += U[q2 * 128 + tid];
      sH[tid] = tanh_(a2);
    }
    bar_lds();

    // ==== Seg 3: O partials — pass1 slot=tid (float4 sH reads); pass2 48
    //      half-slots, 3/wave ====
    {
      {
        const int s = tid;                  // 0..1023 (all valid, < 1048)
        const int q = (s >= 786) ? 3 : (s >= 524) ? 2 : (s >= 262) ? 1 : 0;
        const int P = s - 262 * q;
        const int i0 = 32 * q;
        const float2* p;
        int strideF2;
        if (P < 67) { p = (const float2*)(Wr + i0 * 134 + 2 * P); strideF2 = 67; }
        else        { p = (const float2*)(Ww + i0 * 390 + 2 * (P - 67)); strideF2 = 195; }
        float2 acc = make_float2(0.f, 0.f);
#pragma unroll 2
        for (int k = 0; k < 8; ++k) {
          const float4 hv = *(const float4*)(sH + i0 + 4 * k);
          const float hk[4] = { hv.x, hv.y, hv.z, hv.w };
#pragma unroll
          for (int u = 0; u < 4; ++u) {
            const float2 wv = p[(4 * k + u) * strideF2];
            acc.x = fmaf(hk[u], wv.x, acc.x);
            acc.y = fmaf(hk[u], wv.y, acc.y);
          }
        }
        *(float2*)(U + s * 2) = acc;
      }
      if (lane < 3) {                       // 48 half-slots: former slots 1024..1047
        const int hs = wid * 3 + lane;      // 0..47
        const int e = hs >> 1, hh = hs & 1;
        const int cp = 171 + e;             // Ww col-pair (P = 238+e >= 67)
        const int i0 = 96 + 16 * hh;
        const float2* p = (const float2*)(Ww + i0 * 390 + 2 * cp);
        float2 acc = make_float2(0.f, 0.f);
#pragma unroll 8
        for (int w = 0; w < 16; ++w) {
          const float v = sH[i0 + w];
          const float2 wv = *p;
          acc.x = fmaf(v, wv.x, acc.x);
          acc.y = fmaf(v, wv.y, acc.y);
          p += 195;
        }
        U[2096 + hs * 2]     = acc.x;
        U[2096 + hs * 2 + 1] = acc.y;
      }
      if (tid == 1023) {
        sP[0] = 0.f; sP[1] = 0.f; sP[2] = 0.f; sP[3] = 0.f; sP[4] = 0.f; sP[5] = 0.f;
      }
      bar_lds();
    }

    // ==== Seg F: fused combine+bias / knorm / e,a transforms / key packing /
    //      head scalars / sR zeroing / y-finalize(t-1) ====
    {
      if (tid < 134) {                      // o_r col tid
        float v = 0.f;
#pragma unroll
        for (int q = 0; q < 4; ++q) v += U[tid + 524 * q];
        v += br[tid];
        sOr[tid] = v;
        if (tid < 128) {                    // waves 0,1 whole: |k_r|^2
          float s2 = waveSum(v * v);
          if (lane == 0) atomicAdd(&sP[0], s2);
        }
      } else if (tid == 134) {              // read-head scalars from U directly
        float sc[6];
#pragma unroll
        for (int j = 0; j < 6; ++j) {
          float v = 0.f;
#pragma unroll
          for (int q = 0; q < 4; ++q) v += U[(128 + j) + 524 * q];
          sc[j] = v + br[128 + j];
        }
        sP[80] = softplus_(sc[0]);
        sP[81] = sigmoid_(sc[1]);
        float mx = fmaxf(sc[2], fmaxf(sc[3], sc[4]));
        float e0 = __expf(sc[2] - mx), e1 = __expf(sc[3] - mx), e2 = __expf(sc[4] - mx);
        float es = e0 + e1 + e2;
        sP[82] = e0 / es; sP[83] = e1 / es; sP[84] = e2 / es;
        sP[85] = 1.0f + softplus_(sc[5]);
      } else if (tid == 135) {              // write-head scalars (o_w cols 128..133)
        float sc[6];
#pragma unroll
        for (int j = 0; j < 6; ++j) {
          float v = 0.f;
#pragma unroll
          for (int q = 0; q < 4; ++q) v += U[(262 + j) + 524 * q];
          sc[j] = v + bw[128 + j];
        }
        sP[86] = softplus_(sc[0]);
        sP[87] = sigmoid_(sc[1]);
        float mx = fmaxf(sc[2], fmaxf(sc[3], sc[4]));
        float e0 = __expf(sc[2] - mx), e1 = __expf(sc[3] - mx), e2 = __expf(sc[4] - mx);
        float es = e0 + e1 + e2;
        sP[88] = e0 / es; sP[89] = e1 / es; sP[90] = e2 / es;
        sP[91] = 1.0f + softplus_(sc[5]);
      } else if (tid >= 256 && tid < 512) { // e (256..383) / a (384..511)
        const int cc = tid + 12;            // combined col = 134 + cw, cw = tid-122
        float v = U[cc] + U[cc + 524] + U[cc + 1048];
        if (cc < 476) {
          v += U[cc + 1572];
        } else {                            // q=3 partial split into 2 halves
          const int cw = cc - 134;          // 342..389
          const int e = (cw >> 1) - 171;    // 0..23
          const int base = 2096 + 4 * e + (cw & 1);
          v += U[base] + U[base + 2];
        }
        v += bw[tid - 122];
        sOw[tid - 120] = (tid < 384) ? sigmoid_(v) : tanh_(v);
      } else if (tid >= 512 && tid < 640) { // k_w col cw (waves 8,9 whole): |k_w|^2
        const int cw = tid - 512;
        float v = 0.f;
#pragma unroll
        for (int q = 0; q < 4; ++q) v += U[(134 + cw) + 524 * q];
        v += bw[cw];
        sOw[cw] = v;
        float s2 = waveSum(v * v);
        if (lane == 0) atomicAdd(&sP[1], s2);
      } else if (tid >= 640 && tid < 768) {
        sR[tid - 640] = 0.f;                // Seg-9 ds_add target
      } else if (tid >= 768 && tid < 800) { // bf16 key packing from U (redundant combine)
        const int t2 = tid - 768;
        const int c = t2 & 15;
        union { uint4 v; unsigned short h[8]; } pk;
#pragma unroll
        for (int j = 0; j < 8; ++j) {
          const int col = c * 8 + j;        // 0..127
          float v = 0.f;
#pragma unroll
          for (int q = 0; q < 4; ++q)
            v += U[((t2 < 16) ? col : (134 + col)) + 524 * q];
          v += (t2 < 16) ? br[col] : bw[col];
          pk.h[j] = f2us(v);
        }
        if (t2 < 16) krP[c] = pk.v; else kwP[c] = pk.v;
      } else if (tid >= 896) {              // y-finalize(t-1) on idle waves 14,15
        if (t > 0) {
          const int c = tid - 896;
          float y = bout[c];
#pragma unroll
          for (int q = 0; q < 16; ++q) y += yP[q * 128 + c];
          out[((size_t)b * TSTEPS + (t - 1)) * DIN + c] = y;
        }
      }
      bar_lds();
    }

    // ==== Seg 6 (A): dots + norm + exp fused; bf16 keys; SR/SW via atomic ====
    {
      const float kn_r = sqrtf(sP[0]);
      const float kn_w = sqrtf(sP[1]);
      const float beta_r = sP[80], beta_w = sP[86];
      const int n = tid >> 1, hf = tid & 1;
      const int sw = (n >> 2) & 3;
      float dr = 0.f, dw = 0.f, ss = 0.f;
#pragma unroll
      for (int c = 0; c < 8; ++c) {
        const int cl = hf * 8 + c;
        const uint4 mv = memv[n * 16 + (cl ^ sw)];
        const uint4 kr = krP[cl];
        const uint4 kw = kwP[cl];
        const unsigned mw_[4] = { mv.x, mv.y, mv.z, mv.w };
        const unsigned krw[4] = { kr.x, kr.y, kr.z, kr.w };
        const unsigned kww[4] = { kw.x, kw.y, kw.z, kw.w };
#pragma unroll
        for (int j = 0; j < 4; ++j) {
          const float m0 = bf_lo(mw_[j]), m1 = bf_hi(mw_[j]);
          dr = fmaf(m0, bf_lo(krw[j]), dr); dr = fmaf(m1, bf_hi(krw[j]), dr);
          dw = fmaf(m0, bf_lo(kww[j]), dw); dw = fmaf(m1, bf_hi(kww[j]), dw);
          ss = fmaf(m0, m0, ss);            ss = fmaf(m1, m1, ss);
        }
      }
      dr += __shfl_xor(dr, 1);
      dw += __shfl_xor(dw, 1);
      ss += __shfl_xor(ss, 1);
      const float nr = sqrtf(ss);
      const float er = __expf(beta_r * dr / (nr * kn_r + EPSF));
      const float ew = __expf(beta_w * dw / (nr * kn_w + EPSF));
      if (hf == 0) { eR[n] = er; eW[n] = ew; }
      float s1 = waveSum(er) * 0.5f;
      float s2 = waveSum(ew) * 0.5f;
      if (lane == 0) { atomicAdd(&sP[2], s1); atomicAdd(&sP[3], s2); }
      bar_lds();
    }

    // ==== Seg 7: alpha (tid<512) + Y-top GEMV rows 0..127 (upper waves) ====
    {
      if (tid < NSLOT) {
        const float invE = 1.0f / sP[2];
        const float gr = sP[81], omg = 1.0f - sP[81];
        const int im = (tid - 1) & 511, ip = (tid + 1) & 511;
        const float wgm = gr * (eR[im] * invE) + omg * sWprev[im];
        const float wg0 = gr * (eR[tid] * invE) + omg * sWprev[tid];
        const float wgp = gr * (eR[ip] * invE) + omg * sWprev[ip];
        const float wt = sP[82] * wgp + sP[83] * wg0 + sP[84] * wgm;
        float p1 = (wt > 0.0f) ? __expf(sP[85] * __logf(wt)) : 0.0f;
        float P = waveSum(p1);
        sP1[tid] = p1;
        if (lane == 0) atomicAdd(&sP[4], P);
      } else {
        const int p = tid - 512;
        const int j4 = (p & 31) * 4, sl = p >> 5;   // 16 segs x 8 rows (0..127)
        float4 acc = make_float4(0.f, 0.f, 0.f, 0.f);
#pragma unroll
        for (int w = 0; w < 8; ++w) {
          const float v = sH[8 * sl + w];
          const float4 wv = *(const float4*)(Wout + (8 * sl + w) * DIN + j4);
          acc.x = fmaf(v, wv.x, acc.x); acc.y = fmaf(v, wv.y, acc.y);
          acc.z = fmaf(v, wv.z, acc.z); acc.w = fmaf(v, wv.w, acc.w);
        }
        *(float4*)(yP + sl * 128 + j4) = acc;
      }
      bar_lds();
    }
    // ==== Seg 8: beta (tid<512, writes sWW={w_r,p2}) + x prefetch ====
    {
      if (tid < NSLOT) {
        const float pinv1 = 1.0f / (sP[4] + EPSF);
        const float invE = 1.0f / sP[3];
        const float gw = sP[87], omg = 1.0f - sP[87];
        const int im = (tid - 1) & 511, ip = (tid + 1) & 511;
        const float wgm = gw * (eW[im] * invE) + omg * (sP1[im] * pinv1);
        const float wg0 = gw * (eW[tid] * invE) + omg * (sP1[tid] * pinv1);
        const float wgp = gw * (eW[ip] * invE) + omg * (sP1[ip] * pinv1);
        const float wt = sP[88] * wgp + sP[89] * wg0 + sP[90] * wgm;
        float p2 = (wt > 0.0f) ? __expf(sP[91] * __logf(wt)) : 0.0f;
        float P = waveSum(p2);
        sWW2[tid] = make_float2(sP1[tid] * pinv1, p2);
        if (lane == 0) atomicAdd(&sP[5], P);
      } else if (tid < 512 + DIN && t + 1 < TSTEPS) {
        const int i = tid - 512;
        sXt[i] = x[((size_t)b * TSTEPS + (t + 1)) * DIN + i];
      }
      bar_lds();
    }

    // ==== Seg 9 (B): w_w inline; r-sweep + mem update; r via ds_add into sR ====
    {
      const float pinv2 = 1.0f / (sP[5] + EPSF);
      if (tid < NSLOT) sWprev[tid] = sWW2[tid].y * pinv2;   // next step's w_prev

      const int cl = l ^ ((g >> 2) & 3);
      float4 e4a = *(const float4*)(sOw + 136 + cl * 8);
      float4 e4b = *(const float4*)(sOw + 140 + cl * 8);
      float4 a4a = *(const float4*)(sOw + 264 + cl * 8);
      float4 a4b = *(const float4*)(sOw + 268 + cl * 8);
      const float e8[8] = { e4a.x, e4a.y, e4a.z, e4a.w, e4b.x, e4b.y, e4b.z, e4b.w };
      const float a8[8] = { a4a.x, a4a.y, a4a.z, a4a.w, a4b.x, a4b.y, a4b.z, a4b.w };
      float r8[8] = { 0, 0, 0, 0, 0, 0, 0, 0 };
#pragma unroll 2
      for (int it = 0; it < 8; ++it) {
        const int n = g + 64 * it;
        const float2 wn = sWW2[n];
        const float wrn = wn.x;
        const float wwn = wn.y * pinv2;
        uint4 pk = memv[n * 16 + l];
        const unsigned wds[4] = { pk.x, pk.y, pk.z, pk.w };
        float m[8];
#pragma unroll
        for (int j = 0; j < 4; ++j) { m[2 * j] = bf_lo(wds[j]); m[2 * j + 1] = bf_hi(wds[j]); }
#pragma unroll
        for (int j = 0; j < 8; ++j) {
          r8[j] = fmaf(wrn, m[j], r8[j]);
          const float d = fmaf(-e8[j], m[j], a8[j]);
          m[j] = fmaf(wwn, d, m[j]);
        }
        pk.x = pkbf(m[0], m[1]);
        pk.y = pkbf(m[2], m[3]);
        pk.z = pkbf(m[4], m[5]);
        pk.w = pkbf(m[6], m[7]);
        memv[n * 16 + l] = pk;
      }
#pragma unroll
      for (int j = 0; j < 8; ++j) {          // partners g^1,g^2 share chunk
        r8[j] += __shfl_xor(r8[j], 16);
        r8[j] += __shfl_xor(r8[j], 32);
      }
      if (lane < 16) {                       // 16 waves x 8 ds_add into sR
#pragma unroll
        for (int j = 0; j < 8; ++j) atomicAdd(&sR[cl * 8 + j], r8[j]);
      }
      bar_lds();
    }
    // (Seg 11 for this step runs inside next iteration's Seg 1, or in the
    //  epilogue below for t = TSTEPS-1.)
  }

  // ==== Epilogue: Seg11 for the last step, then final y ====
  if (tid < 512) {
    const int j4 = (tid & 31) * 4, sl = tid >> 5;
    float4 acc = *(const float4*)(yP + sl * 128 + j4);
#pragma unroll
    for (int w = 0; w < 8; ++w) {
      const float v = sR[8 * sl + w];
      const float4 wv = *(const float4*)(Wout + (128 + 8 * sl + w) * DIN + j4);
      acc.x = fmaf(v, wv.x, acc.x); acc.y = fmaf(v, wv.y, acc.y);
      acc.z = fmaf(v, wv.z, acc.z); acc.w = fmaf(v, wv.w, acc.w);
    }
    *(float4*)(yP + sl * 128 + j4) = acc;
  }
  bar_lds();
  if (tid < DIN) {
    float y = bout[tid];
#pragma unroll
    for (int q = 0; q < 16; ++q) y += yP[q * 128 + tid];
    out[((size_t)b * TSTEPS + (TSTEPS - 1)) * DIN + tid] = y;
  }
}

extern "C" void kernel_launch(void* const* d_in, const int* in_sizes, int n_in,
                              void* d_out, int out_size, void* d_ws, size_t ws_size,
                              hipStream_t stream) {
  (void)in_sizes; (void)n_in; (void)out_size; (void)d_ws; (void)ws_size;
  hipFuncSetAttribute(reinterpret_cast<const void*>(ntm_kernel),
                      hipFuncAttributeMaxDynamicSharedMemorySize, (int)LDS_BYTES);
  ntm_kernel<<<dim3(BSZ), dim3(NT), LDS_BYTES, stream>>>(
      (const float*)d_in[0], (const float*)d_in[1], (const float*)d_in[2],
      (const float*)d_in[3], (const float*)d_in[4], (const float*)d_in[5],
      (const float*)d_in[6], (const float*)d_in[7], (const float*)d_in[8],
      (const float*)d_in[9], (const float*)d_in[10],
      (float*)d_out);
}